// Round 4
// baseline (760.873 us; speedup 1.0000x reference)
//
#include <hip/hip_runtime.h>
#include <hip/hip_bf16.h>
#include <stdint.h>

#define T_TOK 2048
#define DM 1024
#define NHEAD 16
#define HDIM 64
#define SEQ 512
#define NEXP 8
#define FFN 4096
#define CAP 512
#define LN_EPSV 1e-5f
#define ROUTER_EPS 1.1920929e-07f

typedef __bf16 bf16x8 __attribute__((ext_vector_type(8)));
typedef float f32x4 __attribute__((ext_vector_type(4)));

// async global->LDS 16B copy. LDS dest must be wave-uniform-base + lane*16
// (our flat-linear layout satisfies this); global src is per-lane.
__device__ __forceinline__ void gld_lds16(const __hip_bfloat16* g, __hip_bfloat16* l) {
  __builtin_amdgcn_global_load_lds(
      (const __attribute__((address_space(1))) void*)g,
      (__attribute__((address_space(3))) void*)l, 16, 0, 0);
}

// XCD-chunked bijective block remap (requires nwg % 8 == 0, true for all our
// MFMA grids). Consecutive remapped ids share an XCD -> L2 reuse of shared
// operand panels. Pure permutation: correctness-neutral.
__device__ __forceinline__ void xcd_remap(int& bx, int& by, int& bz) {
  int gx = gridDim.x, gy = gridDim.y, gz = gridDim.z;
  int nwg = gx * gy * gz;
  int lin = (blockIdx.z * gy + blockIdx.y) * gx + blockIdx.x;
  int q = nwg >> 3;
  int lin2 = (lin & 7) * q + (lin >> 3);
  int gxy = gx * gy;
  bz = lin2 / gxy;
  int rem = lin2 - bz * gxy;
  by = rem / gx;
  bx = rem - by * gx;
}

// ---------------- transpose + fp32->bf16 convert: in [E][R][C] -> out [E][C][R]
__global__ void transpose_cvt(const float* __restrict__ W, __hip_bfloat16* __restrict__ WT,
                              int R, int Cc) {
  __shared__ float tile[32][33];
  int e = blockIdx.z;
  const float* src = W + (size_t)e * R * Cc;
  __hip_bfloat16* dst = WT + (size_t)e * R * Cc;
  int c0 = blockIdx.x * 32, r0 = blockIdx.y * 32;
  int tx = threadIdx.x, ty = threadIdx.y;
#pragma unroll
  for (int i = 0; i < 4; i++) {
    int r = r0 + ty + i * 8;
    tile[ty + i * 8][tx] = src[(size_t)r * Cc + c0 + tx];
  }
  __syncthreads();
#pragma unroll
  for (int i = 0; i < 4; i++) {
    int c = c0 + ty + i * 8;
    dst[(size_t)c * R + r0 + tx] = __float2bfloat16(tile[tx][ty + i * 8]);
  }
}

// ---------------- transpose + split fp32 -> (hi,lo) bf16 pair: [R][C] -> [C][R], *scale
__global__ void transpose_cvt_hp(const float* __restrict__ W, __hip_bfloat16* __restrict__ WH,
                                 __hip_bfloat16* __restrict__ WL, int R, int Cc, float scale) {
  __shared__ float tile[32][33];
  int c0 = blockIdx.x * 32, r0 = blockIdx.y * 32;
  int tx = threadIdx.x, ty = threadIdx.y;
#pragma unroll
  for (int i = 0; i < 4; i++) {
    int r = r0 + ty + i * 8;
    tile[ty + i * 8][tx] = W[(size_t)r * Cc + c0 + tx];
  }
  __syncthreads();
#pragma unroll
  for (int i = 0; i < 4; i++) {
    int c = c0 + ty + i * 8;
    float v = tile[tx][ty + i * 8] * scale;
    __hip_bfloat16 h = __float2bfloat16(v);
    WH[(size_t)c * R + r0 + tx] = h;
    WL[(size_t)c * R + r0 + tx] = __float2bfloat16(v - __bfloat162float(h));
  }
}

// ---------------- pack scaled biases for batched QKV: [bq*0.125 | bk | bv]
__global__ __launch_bounds__(256) void pack_bias(const float* __restrict__ bq,
                                                 const float* __restrict__ bk,
                                                 const float* __restrict__ bv,
                                                 float* __restrict__ outp) {
  int t = blockIdx.x * 256 + threadIdx.x;
  if (t < DM) outp[t] = bq[t] * 0.125f;
  else if (t < 2 * DM) outp[t] = bk[t - DM];
  else if (t < 3 * DM) outp[t] = bv[t - 2 * DM];
}

// ---------------- LayerNorm fp32 -> (hi,lo) bf16 pair, one block per row
__global__ __launch_bounds__(256) void ln1_hp(const float* __restrict__ x,
                                              const float* __restrict__ g,
                                              const float* __restrict__ bta,
                                              __hip_bfloat16* __restrict__ ohi,
                                              __hip_bfloat16* __restrict__ olo) {
  int row = blockIdx.x, t = threadIdx.x;
  const float4* xr = (const float4*)(x + (size_t)row * DM);
  float4 v = xr[t];
  float s = v.x + v.y + v.z + v.w;
  float ss = v.x * v.x + v.y * v.y + v.z * v.z + v.w * v.w;
  __shared__ float rs[4], rss[4];
  __shared__ float smu, sinv;
  int wid = t >> 6, lane = t & 63;
  for (int off = 32; off; off >>= 1) { s += __shfl_down(s, off); ss += __shfl_down(ss, off); }
  if (!lane) { rs[wid] = s; rss[wid] = ss; }
  __syncthreads();
  if (!t) {
    float S = rs[0] + rs[1] + rs[2] + rs[3], SS = rss[0] + rss[1] + rss[2] + rss[3];
    float mu = S / DM;
    float var = SS / DM - mu * mu;
    smu = mu; sinv = 1.0f / sqrtf(var + LN_EPSV);
  }
  __syncthreads();
  float mu = smu, inv = sinv;
  float4 gv = ((const float4*)g)[t], bv = ((const float4*)bta)[t];
  float n[4];
  n[0] = (v.x - mu) * inv * gv.x + bv.x;
  n[1] = (v.y - mu) * inv * gv.y + bv.y;
  n[2] = (v.z - mu) * inv * gv.z + bv.z;
  n[3] = (v.w - mu) * inv * gv.w + bv.w;
  __hip_bfloat16* hr = ohi + (size_t)row * DM + t * 4;
  __hip_bfloat16* lr = olo + (size_t)row * DM + t * 4;
#pragma unroll
  for (int k = 0; k < 4; k++) {
    __hip_bfloat16 h = __float2bfloat16(n[k]);
    hr[k] = h;
    lr[k] = __float2bfloat16(n[k] - __bfloat162float(h));
  }
}

// ---------------- fp32 -> (hi,lo) bf16 split convert
__global__ __launch_bounds__(256) void cvt_hp(const float* __restrict__ in,
                                              __hip_bfloat16* __restrict__ hi,
                                              __hip_bfloat16* __restrict__ lo) {
  int i = (blockIdx.x * 256 + threadIdx.x) * 4;
  float4 v = *(const float4*)&in[i];
  float n[4] = {v.x, v.y, v.z, v.w};
#pragma unroll
  for (int k = 0; k < 4; k++) {
    __hip_bfloat16 h = __float2bfloat16(n[k]);
    hi[i + k] = h;
    lo[i + k] = __float2bfloat16(n[k] - __bfloat162float(h));
  }
}

// ---------------- fp32 tiled GEMM. C = (A@B(^T) + bias)*scale + resid
template <int BM, int BN, int TM, int TN, bool BT>
__global__ __launch_bounds__(256) void gemm_f32(
    const float* __restrict__ A, const float* __restrict__ B, float* __restrict__ Cc,
    const float* __restrict__ bias, const float* __restrict__ resid,
    int M, int N, int K, int lda, int ldb, int ldc, float scale, int zdiv,
    long long sA1, long long sA2, long long sB1, long long sB2,
    long long sC1, long long sC2) {
  constexpr int BK = 16;
  __shared__ float As[BK][BM + 4];
  __shared__ float Bs[BK][BN + 4];
  int z = blockIdx.z;
  int zq = z / zdiv, zr = z % zdiv;
  A += zq * sA1 + zr * sA2;
  B += zq * sB1 + zr * sB2;
  Cc += zq * sC1 + zr * sC2;
  int tid = threadIdx.x;
  int m0 = blockIdx.y * BM, n0 = blockIdx.x * BN;
  constexpr int NTX = BN / TN;
  int tx = tid % NTX, ty = tid / NTX;
  float acc[TM][TN] = {};
  for (int k0 = 0; k0 < K; k0 += BK) {
    constexpr int ALOADS = BM * BK / (256 * 4);
#pragma unroll
    for (int i = 0; i < ALOADS; i++) {
      int idx = tid + i * 256;
      int m = idx / (BK / 4);
      int kk = (idx % (BK / 4)) * 4;
      float4 va = *(const float4*)&A[(size_t)(m0 + m) * lda + k0 + kk];
      As[kk + 0][m] = va.x; As[kk + 1][m] = va.y; As[kk + 2][m] = va.z; As[kk + 3][m] = va.w;
    }
    constexpr int BLOADS = BK * BN / (256 * 4);
    if (!BT) {
#pragma unroll
      for (int i = 0; i < BLOADS; i++) {
        int idx = tid + i * 256;
        int kk = idx / (BN / 4);
        int n = (idx % (BN / 4)) * 4;
        *(float4*)&Bs[kk][n] = *(const float4*)&B[(size_t)(k0 + kk) * ldb + n0 + n];
      }
    } else {
#pragma unroll
      for (int i = 0; i < BLOADS; i++) {
        int idx = tid + i * 256;
        int n = idx / (BK / 4);
        int kk = (idx % (BK / 4)) * 4;
        float4 vb = *(const float4*)&B[(size_t)(n0 + n) * ldb + k0 + kk];
        Bs[kk + 0][n] = vb.x; Bs[kk + 1][n] = vb.y; Bs[kk + 2][n] = vb.z; Bs[kk + 3][n] = vb.w;
      }
    }
    __syncthreads();
#pragma unroll
    for (int kk = 0; kk < BK; kk++) {
      float ar[TM], br[TN];
#pragma unroll
      for (int i = 0; i < TM; i += 4) *(float4*)&ar[i] = *(const float4*)&As[kk][ty * TM + i];
#pragma unroll
      for (int j = 0; j < TN; j += 4) *(float4*)&br[j] = *(const float4*)&Bs[kk][tx * TN + j];
#pragma unroll
      for (int i = 0; i < TM; i++)
#pragma unroll
        for (int j = 0; j < TN; j++) acc[i][j] += ar[i] * br[j];
    }
    __syncthreads();
  }
#pragma unroll
  for (int i = 0; i < TM; i++) {
    int m = m0 + ty * TM + i;
#pragma unroll
    for (int j = 0; j < TN; j++) {
      int n = n0 + tx * TN + j;
      float v = acc[i][j];
      if (bias) v += bias[n];
      v *= scale;
      if (resid) v += resid[(size_t)m * ldc + n];
      acc[i][j] = v;
    }
#pragma unroll
    for (int j = 0; j < TN; j += 4)
      *(float4*)&Cc[(size_t)m * ldc + n0 + tx * TN + j] = *(float4*)&acc[i][j];
  }
}

// ---------------- row softmax in place (rows of 512 fp32)
__global__ __launch_bounds__(256) void softmax_rows(float* __restrict__ sc) {
  int row = blockIdx.x, t = threadIdx.x;
  float* p = sc + (size_t)row * SEQ;
  float2 v = *(const float2*)&p[t * 2];
  float mx = fmaxf(v.x, v.y);
  __shared__ float r[4];
  __shared__ float bmax, bsum;
  int wid = t >> 6, lane = t & 63;
  for (int off = 32; off; off >>= 1) mx = fmaxf(mx, __shfl_down(mx, off));
  if (!lane) r[wid] = mx;
  __syncthreads();
  if (!t) bmax = fmaxf(fmaxf(r[0], r[1]), fmaxf(r[2], r[3]));
  __syncthreads();
  mx = bmax;
  float e0 = __expf(v.x - mx), e1v = __expf(v.y - mx);
  float s = e0 + e1v;
  for (int off = 32; off; off >>= 1) s += __shfl_down(s, off);
  if (!lane) r[wid] = s;
  __syncthreads();
  if (!t) bsum = r[0] + r[1] + r[2] + r[3];
  __syncthreads();
  float inv = 1.0f / bsum;
  float2 o; o.x = e0 * inv; o.y = e1v * inv;
  *(float2*)&p[t * 2] = o;
}

// ---------------- split-precision bf16 MFMA GEMM (fp32-accurate), double-buffered:
// C = A @ Bt^T + bias (+resid), A = Ahi+Alo, Bt = Bhi+Blo, [M,K]x[N,K]
// acc += AhiBhi + AhiBlo + AloBhi  (lo*lo term ~2^-18, dropped)
// MODE 2: (acc+bias) -> fp32 ; MODE 3: (acc+bias)+resid -> fp32
template <int MODE>
__global__ __launch_bounds__(256) void gemm_hp(
    const __hip_bfloat16* __restrict__ Ahi, const __hip_bfloat16* __restrict__ Alo,
    const __hip_bfloat16* __restrict__ Bhi, const __hip_bfloat16* __restrict__ Blo,
    float* __restrict__ Cc, const float* __restrict__ bias, const float* __restrict__ resid,
    int M, int N, int K, long long sB, long long sC, int biasStride) {
  constexpr int BM = 128, BN = 128, BK = 32;
  // 2-deep double buffer: 2 x 4 arrays x 8KB = 64KB -> 2 blocks/CU
  __shared__ __align__(16) __hip_bfloat16 AsH[2][BM * BK];
  __shared__ __align__(16) __hip_bfloat16 AsL[2][BM * BK];
  __shared__ __align__(16) __hip_bfloat16 BsH[2][BN * BK];
  __shared__ __align__(16) __hip_bfloat16 BsL[2][BN * BK];
  int bx, by, bz;
  xcd_remap(bx, by, bz);
  int e = bz;
  Bhi += (size_t)e * sB; Blo += (size_t)e * sB;
  size_t czoff = (size_t)e * sC;
  const float* bvec = bias + (size_t)e * biasStride;
  int m0 = by * BM, n0 = bx * BN;
  int tid = threadIdx.x;
  int lane = tid & 63, quad = lane >> 4, l16 = lane & 15, wv = tid >> 6;
  int wm = wv >> 1, wn = wv & 1;
  f32x4 acc[4][4] = {};
  // staging: linear LDS dest, swizzle folded into GLOBAL source chunk.
  // swizzle pc = lc ^ ((r>>1)&3): exactly 2-way bank aliasing on ds_read (free).
  auto STAGE = [&](int buf, int k0) {
#pragma unroll
    for (int i = 0; i < 2; i++) {
      int flat = tid + i * 256;       // 512 chunks of 8 bf16 = 128 rows x 4 chunks
      int r = flat >> 2, lc = flat & 3;
      int pc = lc ^ ((r >> 1) & 3);
      gld_lds16(Ahi + (size_t)(m0 + r) * K + k0 + pc * 8, &AsH[buf][flat * 8]);
      gld_lds16(Alo + (size_t)(m0 + r) * K + k0 + pc * 8, &AsL[buf][flat * 8]);
      gld_lds16(Bhi + (size_t)(n0 + r) * K + k0 + pc * 8, &BsH[buf][flat * 8]);
      gld_lds16(Blo + (size_t)(n0 + r) * K + k0 + pc * 8, &BsL[buf][flat * 8]);
    }
  };
  STAGE(0, 0);
  __syncthreads();
  int KT = K / BK;
  for (int kt = 0; kt < KT; kt++) {
    int cur = kt & 1;
    if (kt + 1 < KT) STAGE(cur ^ 1, (kt + 1) * BK);  // in flight during MFMA below
    bf16x8 ah[4], al[4], bh[4], bl[4];
#pragma unroll
    for (int i = 0; i < 4; i++) {
      int r = wm * 64 + i * 16 + l16;
      int pc = quad ^ ((r >> 1) & 3);
      ah[i] = *(const bf16x8*)(&AsH[cur][r * BK + pc * 8]);
      al[i] = *(const bf16x8*)(&AsL[cur][r * BK + pc * 8]);
    }
#pragma unroll
    for (int j = 0; j < 4; j++) {
      int r = wn * 64 + j * 16 + l16;
      int pc = quad ^ ((r >> 1) & 3);
      bh[j] = *(const bf16x8*)(&BsH[cur][r * BK + pc * 8]);
      bl[j] = *(const bf16x8*)(&BsL[cur][r * BK + pc * 8]);
    }
#pragma unroll
    for (int i = 0; i < 4; i++)
#pragma unroll
      for (int j = 0; j < 4; j++) {
        acc[i][j] = __builtin_amdgcn_mfma_f32_16x16x32_bf16(ah[i], bh[j], acc[i][j], 0, 0, 0);
        acc[i][j] = __builtin_amdgcn_mfma_f32_16x16x32_bf16(ah[i], bl[j], acc[i][j], 0, 0, 0);
        acc[i][j] = __builtin_amdgcn_mfma_f32_16x16x32_bf16(al[i], bh[j], acc[i][j], 0, 0, 0);
      }
    __syncthreads();  // drains prefetch + protects cur from next overwrite
  }
#pragma unroll
  for (int j = 0; j < 4; j++) {
    int col = n0 + wn * 64 + j * 16 + l16;
    float bb = bvec[col];
#pragma unroll
    for (int i = 0; i < 4; i++) {
      int row0 = m0 + wm * 64 + i * 16 + quad * 4;
#pragma unroll
      for (int r = 0; r < 4; r++) {
        float v = acc[i][j][r] + bb;
        if (MODE == 3) v += resid[(size_t)(row0 + r) * N + col];
        Cc[czoff + (size_t)(row0 + r) * N + col] = v;
      }
    }
  }
}

// ---------------- LN2 fused with router logits; writes h2 (bf16) and logits (fp32)
__global__ __launch_bounds__(256) void ln2_router(const float* __restrict__ x2,
                                                  const float* __restrict__ g,
                                                  const float* __restrict__ bta,
                                                  const float* __restrict__ wr,
                                                  __hip_bfloat16* __restrict__ h2,
                                                  float* __restrict__ logits) {
  int row = blockIdx.x, t = threadIdx.x;
  const float4* xr = (const float4*)(x2 + (size_t)row * DM);
  float4 v = xr[t];
  float s = v.x + v.y + v.z + v.w;
  float ss = v.x * v.x + v.y * v.y + v.z * v.z + v.w * v.w;
  __shared__ float rs[4], rss[4];
  __shared__ float smu, sinv;
  int wid = t >> 6, lane = t & 63;
  for (int off = 32; off; off >>= 1) { s += __shfl_down(s, off); ss += __shfl_down(ss, off); }
  if (!lane) { rs[wid] = s; rss[wid] = ss; }
  __syncthreads();
  if (!t) {
    float S = rs[0] + rs[1] + rs[2] + rs[3], SS = rss[0] + rss[1] + rss[2] + rss[3];
    float mu = S / DM;
    float var = SS / DM - mu * mu;
    smu = mu; sinv = 1.0f / sqrtf(var + LN_EPSV);
  }
  __syncthreads();
  float mu = smu, inv = sinv;
  float4 gv = ((const float4*)g)[t], bv = ((const float4*)bta)[t];
  float n0 = (v.x - mu) * inv * gv.x + bv.x;
  float n1 = (v.y - mu) * inv * gv.y + bv.y;
  float n2 = (v.z - mu) * inv * gv.z + bv.z;
  float n3 = (v.w - mu) * inv * gv.w + bv.w;
  __hip_bfloat16* hr = h2 + (size_t)row * DM + t * 4;
  hr[0] = __float2bfloat16(n0); hr[1] = __float2bfloat16(n1);
  hr[2] = __float2bfloat16(n2); hr[3] = __float2bfloat16(n3);
  const float* w0 = wr + (size_t)(t * 4) * NEXP;
  __shared__ float red[256 * NEXP];
#pragma unroll
  for (int e = 0; e < NEXP; e++)
    red[t * NEXP + e] = n0 * w0[e] + n1 * w0[NEXP + e] + n2 * w0[2 * NEXP + e] + n3 * w0[3 * NEXP + e];
  __syncthreads();
  for (int sdt = 128; sdt > 0; sdt >>= 1) {
    if (t < sdt) {
#pragma unroll
      for (int e = 0; e < NEXP; e++) red[t * NEXP + e] += red[(t + sdt) * NEXP + e];
    }
    __syncthreads();
  }
  if (t < NEXP) logits[(size_t)row * NEXP + t] = red[t];
}

// ---------------- routing: top1/top2, deterministic capacity ranks, gates, dispatch map
__global__ __launch_bounds__(256) void routing(const float* __restrict__ logits,
                                               int* __restrict__ e1o, int* __restrict__ s1o,
                                               float* __restrict__ g1o,
                                               int* __restrict__ e2o, int* __restrict__ s2o,
                                               float* __restrict__ g2o,
                                               int* __restrict__ src_tok) {
  __shared__ unsigned char t1s[T_TOK], t2s[T_TOK];
  __shared__ unsigned short r1s[T_TOK], r2s[T_TOK];
  __shared__ int cnt1s[NEXP];
  int t = threadIdx.x;
  for (int i = t; i < NEXP * CAP; i += 256) src_tok[i] = -1;
  for (int tok = t; tok < T_TOK; tok += 256) {
    float lg[NEXP];
#pragma unroll
    for (int e = 0; e < NEXP; e++) lg[e] = logits[(size_t)tok * NEXP + e];
    int b1 = 0; float m1v = lg[0];
#pragma unroll
    for (int e = 1; e < NEXP; e++) if (lg[e] > m1v) { m1v = lg[e]; b1 = e; }
    int b2 = -1; float m2v = -3.4e38f;
#pragma unroll
    for (int e = 0; e < NEXP; e++) if (e != b1 && lg[e] > m2v) { m2v = lg[e]; b2 = e; }
    t1s[tok] = (unsigned char)b1; t2s[tok] = (unsigned char)b2;
  }
  __syncthreads();
  if (t < 64) {
    int base[NEXP] = {0, 0, 0, 0, 0, 0, 0, 0};
    for (int c = 0; c < T_TOK / 64; c++) {
      int tok = c * 64 + t;
      int my = t1s[tok];
      unsigned long long below = (1ull << t) - 1ull;
#pragma unroll
      for (int e = 0; e < NEXP; e++) {
        unsigned long long msk = __ballot(my == e);
        if (my == e) r1s[tok] = (unsigned short)(base[e] + __popcll(msk & below));
        base[e] += (int)__popcll(msk);
      }
    }
    if (t == 0) {
#pragma unroll
      for (int e = 0; e < NEXP; e++) cnt1s[e] = base[e];
    }
#pragma unroll
    for (int e = 0; e < NEXP; e++) base[e] = 0;
    for (int c = 0; c < T_TOK / 64; c++) {
      int tok = c * 64 + t;
      int my = t2s[tok];
      unsigned long long below = (1ull << t) - 1ull;
#pragma unroll
      for (int e = 0; e < NEXP; e++) {
        unsigned long long msk = __ballot(my == e);
        if (my == e) r2s[tok] = (unsigned short)(base[e] + __popcll(msk & below));
        base[e] += (int)__popcll(msk);
      }
    }
  }
  __syncthreads();
  for (int tok = t; tok < T_TOK; tok += 256) {
    float lg[NEXP];
#pragma unroll
    for (int e = 0; e < NEXP; e++) lg[e] = logits[(size_t)tok * NEXP + e];
    int b1 = t1s[tok], b2 = t2s[tok];
    float lb1 = lg[0], lb2 = lg[0];
#pragma unroll
    for (int e = 0; e < NEXP; e++) { if (e == b1) lb1 = lg[e]; if (e == b2) lb2 = lg[e]; }
    float sum = 0.f;
#pragma unroll
    for (int e = 0; e < NEXP; e++) sum += __expf(lg[e] - lb1);
    float p1 = 1.0f / sum;
    float p2 = __expf(lb2 - lb1) / sum;
    int sl1 = r1s[tok];
    int sl2 = r2s[tok] + cnt1s[b2];
    bool v1 = sl1 < CAP, v2 = sl2 < CAP;
    float tt1 = v1 ? p1 : 0.f, tt2 = v2 ? p2 : 0.f;
    float den = fmaxf(tt1 + tt2, ROUTER_EPS);
    float gg1 = v1 ? tt1 / den : 0.f;
    float gg2 = v2 ? tt2 / den : 0.f;
    e1o[tok] = b1; s1o[tok] = v1 ? sl1 : 0; g1o[tok] = gg1;
    e2o[tok] = b2; s2o[tok] = v2 ? sl2 : 0; g2o[tok] = gg2;
    if (v1) src_tok[b1 * CAP + sl1] = tok;
    if (v2) src_tok[b2 * CAP + sl2] = tok;
  }
}

// ---------------- dispatch h2 rows into [E*CAP, DM] bf16 buffers (zero unfilled)
__global__ __launch_bounds__(64) void dispatch(const int* __restrict__ src_tok,
                                               const __hip_bfloat16* __restrict__ h2,
                                               __hip_bfloat16* __restrict__ Amoe) {
  int rowb = blockIdx.x, t = threadIdx.x;
  int tok = src_tok[rowb];
  uint4* dst = (uint4*)(Amoe + (size_t)rowb * DM);
  if (tok >= 0) {
    const uint4* src = (const uint4*)(h2 + (size_t)tok * DM);
    dst[t] = src[t]; dst[t + 64] = src[t + 64];
  } else {
    uint4 z = make_uint4(0, 0, 0, 0);
    dst[t] = z; dst[t + 64] = z;
  }
}

// ---------------- bf16 MFMA GEMM, double-buffered: C = epi(A @ Bt^T + bias)
// MODE 0: relu(acc+bias) -> bf16 ; MODE 1: (acc+bias)*0.8 -> bf16
template <int MODE>
__global__ __launch_bounds__(256) void gemm_bf16(
    const __hip_bfloat16* __restrict__ A, const __hip_bfloat16* __restrict__ Bt,
    __hip_bfloat16* __restrict__ Cc, const float* __restrict__ bias,
    int M, int N, int K, long long sA, long long sB, long long sC, int biasStride) {
  constexpr int BM = 128, BN = 128, BK = 64;
  // 2-deep double buffer: 2 x 2 arrays x 16KB = 64KB -> 2 blocks/CU
  __shared__ __align__(16) __hip_bfloat16 Asm[2][BM * BK];
  __shared__ __align__(16) __hip_bfloat16 Bsm[2][BN * BK];
  int bx, by, bz;
  xcd_remap(bx, by, bz);
  int e = bz;
  A += (size_t)e * sA; Bt += (size_t)e * sB; Cc += (size_t)e * sC;
  const float* bvec = bias + (size_t)e * biasStride;
  int m0 = by * BM, n0 = bx * BN;
  int tid = threadIdx.x;
  int lane = tid & 63, quad = lane >> 4, l16 = lane & 15, wv = tid >> 6;
  int wm = wv >> 1, wn = wv & 1;
  f32x4 acc[4][4] = {};
  auto STAGE = [&](int buf, int k0) {
#pragma unroll
    for (int i = 0; i < 4; i++) {
      int flat = tid + i * 256;       // 1024 chunks of 8 bf16 = 128 rows x 8 chunks
      int r = flat >> 3, lc = flat & 7;
      int pc = lc ^ (r & 7);          // swizzle folded into global source chunk
      gld_lds16(A + (size_t)(m0 + r) * K + k0 + pc * 8, &Asm[buf][flat * 8]);
      gld_lds16(Bt + (size_t)(n0 + r) * K + k0 + pc * 8, &Bsm[buf][flat * 8]);
    }
  };
  STAGE(0, 0);
  __syncthreads();
  int KT = K / BK;
  for (int kt = 0; kt < KT; kt++) {
    int cur = kt & 1;
    if (kt + 1 < KT) STAGE(cur ^ 1, (kt + 1) * BK);  // in flight during MFMA below
#pragma unroll
    for (int ks = 0; ks < 2; ks++) {
      bf16x8 af[4], bfr[4];
#pragma unroll
      for (int i = 0; i < 4; i++) {
        int r = wm * 64 + i * 16 + l16;
        int pc = (ks * 4 + quad) ^ (r & 7);
        af[i] = *(const bf16x8*)(&Asm[cur][r * BK + pc * 8]);
      }
#pragma unroll
      for (int j = 0; j < 4; j++) {
        int r = wn * 64 + j * 16 + l16;
        int pc = (ks * 4 + quad) ^ (r & 7);
        bfr[j] = *(const bf16x8*)(&Bsm[cur][r * BK + pc * 8]);
      }
#pragma unroll
      for (int i = 0; i < 4; i++)
#pragma unroll
        for (int j = 0; j < 4; j++)
          acc[i][j] = __builtin_amdgcn_mfma_f32_16x16x32_bf16(af[i], bfr[j], acc[i][j], 0, 0, 0);
    }
    __syncthreads();  // drains prefetch + protects cur from next overwrite
  }
#pragma unroll
  for (int j = 0; j < 4; j++) {
    int col = n0 + wn * 64 + j * 16 + l16;
    float bb = bvec[col];
#pragma unroll
    for (int i = 0; i < 4; i++) {
      int row0 = m0 + wm * 64 + i * 16 + quad * 4;
#pragma unroll
      for (int r = 0; r < 4; r++) {
        float v = acc[i][j][r] + bb;
        if (MODE == 0) v = fmaxf(v, 0.0f);
        else v *= 0.8f;
        Cc[(size_t)(row0 + r) * N + col] = __float2bfloat16(v);
      }
    }
  }
}

// ---------------- combine: out = x2 + g1*Y[e1,s1] + g2*Y[e2,s2]
__global__ __launch_bounds__(64) void combine(const float* __restrict__ x2,
                                              const __hip_bfloat16* __restrict__ Y,
                                              const int* __restrict__ e1, const int* __restrict__ s1,
                                              const float* __restrict__ g1,
                                              const int* __restrict__ e2, const int* __restrict__ s2,
                                              const float* __restrict__ g2,
                                              float* __restrict__ out) {
  int tok = blockIdx.x, t = threadIdx.x;
  float gg1 = g1[tok], gg2 = g2[tok];
  const __hip_bfloat16* y1 = Y + ((size_t)e1[tok] * CAP + s1[tok]) * DM;
  const __hip_bfloat16* y2 = Y + ((size_t)e2[tok] * CAP + s2[tok]) * DM;
  const float* xr = x2 + (size_t)tok * DM;
  float* orow = out + (size_t)tok * DM;
#pragma unroll
  for (int j = 0; j < 4; j++) {
    int idx = t * 4 + j * 256;
    float4 vv = *(const float4*)&xr[idx];
    float4 r;
    r.x = vv.x + gg1 * __bfloat162float(y1[idx + 0]) + gg2 * __bfloat162float(y2[idx + 0]);
    r.y = vv.y + gg1 * __bfloat162float(y1[idx + 1]) + gg2 * __bfloat162float(y2[idx + 1]);
    r.z = vv.z + gg1 * __bfloat162float(y1[idx + 2]) + gg2 * __bfloat162float(y2[idx + 2]);
    r.w = vv.w + gg1 * __bfloat162float(y1[idx + 3]) + gg2 * __bfloat162float(y2[idx + 3]);
    *(float4*)&orow[idx] = r;
  }
}

extern "C" void kernel_launch(void* const* d_in, const int* in_sizes, int n_in,
                              void* d_out, int out_size, void* d_ws, size_t ws_size,
                              hipStream_t stream) {
  (void)in_sizes; (void)n_in; (void)out_size; (void)ws_size;
  const float* x    = (const float*)d_in[0];
  const float* wq   = (const float*)d_in[1];
  const float* bq   = (const float*)d_in[2];
  const float* wk   = (const float*)d_in[3];
  const float* bk   = (const float*)d_in[4];
  const float* wv   = (const float*)d_in[5];
  const float* bv   = (const float*)d_in[6];
  const float* wo   = (const float*)d_in[7];
  const float* bo   = (const float*)d_in[8];
  const float* ln1g = (const float*)d_in[9];
  const float* ln1b = (const float*)d_in[10];
  const float* ln2g = (const float*)d_in[11];
  const float* ln2b = (const float*)d_in[12];
  const float* wr   = (const float*)d_in[13];
  const float* w1   = (const float*)d_in[14];
  const float* b1   = (const float*)d_in[15];
  const float* w2   = (const float*)d_in[16];
  const float* b2   = (const float*)d_in[17];
  float* out = (float*)d_out;
  char* ws = (char*)d_ws;

  // ---------------- workspace arena (max ~230 MB; regions reused once dead)
  __hip_bfloat16* W1T  = (__hip_bfloat16*)(ws + 0);
  __hip_bfloat16* W2T  = (__hip_bfloat16*)(ws + 67108864);
  float* sc            = (float*)(ws + 134217728);
  __hip_bfloat16* h1hi = (__hip_bfloat16*)(ws + 134217728);
  __hip_bfloat16* h1lo = (__hip_bfloat16*)(ws + 138412032);
  float* bqkv          = (float*)(ws + 142606336);
  __hip_bfloat16* WQKVH= (__hip_bfloat16*)(ws + 143654912);
  __hip_bfloat16* WQKVL= (__hip_bfloat16*)(ws + 149946368);
  __hip_bfloat16* Hm   = (__hip_bfloat16*)(ws + 134217728);
  float* logits        = (float*)(ws + 167772160);
  int*   e1a           = (int*)(ws + 167837696);
  int*   s1a           = (int*)(ws + 167845888);
  int*   e2a           = (int*)(ws + 167854080);
  int*   s2a           = (int*)(ws + 167862272);
  float* g1a           = (float*)(ws + 167870464);
  float* g2a           = (float*)(ws + 167878656);
  int*   src_tok       = (int*)(ws + 167886848);
  float* qkv           = (float*)(ws + 201326592);
  float* q             = qkv;
  float* k_            = qkv + 2097152;
  float* v             = qkv + 4194304;
  float* o_f           = (float*)(ws + 201326592);
  float* x2            = (float*)(ws + 201326592);
  __hip_bfloat16* ohi  = (__hip_bfloat16*)(ws + 209715200);
  __hip_bfloat16* olo  = (__hip_bfloat16*)(ws + 213909504);
  __hip_bfloat16* Y    = (__hip_bfloat16*)(ws + 209715200);
  __hip_bfloat16* h2   = (__hip_bfloat16*)(ws + 218103808);
  __hip_bfloat16* Amoe = (__hip_bfloat16*)(ws + 222298112);
  __hip_bfloat16* WOH  = (__hip_bfloat16*)(ws + 226492416);
  __hip_bfloat16* WOL  = (__hip_bfloat16*)(ws + 228589568);

  // 1. MoE weight convert+transpose (plain bf16 — post-routing path)
  transpose_cvt<<<dim3(FFN / 32, DM / 32, NEXP), dim3(32, 8), 0, stream>>>(w1, W1T, DM, FFN);
  transpose_cvt<<<dim3(DM / 32, FFN / 32, NEXP), dim3(32, 8), 0, stream>>>(w2, W2T, FFN, DM);
  // 2. attention weight transposes -> split hi/lo bf16 [N,K]; fold 0.125 into wq
  transpose_cvt_hp<<<dim3(DM / 32, DM / 32, 1), dim3(32, 8), 0, stream>>>(
      wq, WQKVH, WQKVL, DM, DM, 0.125f);
  transpose_cvt_hp<<<dim3(DM / 32, DM / 32, 1), dim3(32, 8), 0, stream>>>(
      wk, WQKVH + (size_t)DM * DM, WQKVL + (size_t)DM * DM, DM, DM, 1.0f);
  transpose_cvt_hp<<<dim3(DM / 32, DM / 32, 1), dim3(32, 8), 0, stream>>>(
      wv, WQKVH + (size_t)2 * DM * DM, WQKVL + (size_t)2 * DM * DM, DM, DM, 1.0f);
  transpose_cvt_hp<<<dim3(DM / 32, DM / 32, 1), dim3(32, 8), 0, stream>>>(
      wo, WOH, WOL, DM, DM, 1.0f);
  pack_bias<<<3 * DM / 256, 256, 0, stream>>>(bq, bk, bv, bqkv);
  // 3. LN1 -> split hi/lo bf16
  ln1_hp<<<T_TOK, 256, 0, stream>>>(x, ln1g, ln1b, h1hi, h1lo);
  // 4. batched Q,K,V projections (split-precision MFMA, fp32-accurate) -> fp32
  gemm_hp<2><<<dim3(DM / 128, T_TOK / 128, 3), 256, 0, stream>>>(
      h1hi, h1lo, WQKVH, WQKVL, qkv, bqkv, nullptr, T_TOK, DM, DM,
      (long long)DM * DM, (long long)T_TOK * DM, DM);
  // 5. scores = Q K^T per head (fp32)
  gemm_f32<128, 128, 8, 8, true><<<dim3(SEQ / 128, SEQ / 128, 64), 256, 0, stream>>>(
      q, k_, sc, nullptr, nullptr, SEQ, SEQ, HDIM, DM, DM, SEQ, 1.0f, NHEAD,
      (long long)SEQ * DM, HDIM, (long long)SEQ * DM, HDIM,
      (long long)NHEAD * SEQ * SEQ, (long long)SEQ * SEQ);
  // 6. softmax rows
  softmax_rows<<<64 * SEQ, 256, 0, stream>>>(sc);
  // 7. O = P V per head (fp32)
  gemm_f32<128, 64, 8, 4, false><<<dim3(1, SEQ / 128, 64), 256, 0, stream>>>(
      sc, v, o_f, nullptr, nullptr, SEQ, HDIM, SEQ, SEQ, DM, DM, 1.0f, NHEAD,
      (long long)NHEAD * SEQ * SEQ, (long long)SEQ * SEQ,
      (long long)SEQ * DM, HDIM, (long long)SEQ * DM, HDIM);
  // 8. split O to hi/lo bf16
  cvt_hp<<<T_TOK * DM / 1024, 256, 0, stream>>>(o_f, ohi, olo);
  // 9. O-proj (split-precision MFMA) + residual -> x2 fp32
  gemm_hp<3><<<dim3(DM / 128, T_TOK / 128, 1), 256, 0, stream>>>(
      ohi, olo, WOH, WOL, x2, bo, x, T_TOK, DM, DM, 0LL, 0LL, 0);
  // 10. LN2 + router logits
  ln2_router<<<T_TOK, 256, 0, stream>>>(x2, ln2g, ln2b, wr, h2, logits);
  // 11. routing decisions
  routing<<<1, 256, 0, stream>>>(logits, e1a, s1a, g1a, e2a, s2a, g2a, src_tok);
  // 12. dispatch to expert capacity buffers
  dispatch<<<NEXP * CAP, 64, 0, stream>>>(src_tok, h2, Amoe);
  // 13. FFN1: relu(Amoe @ w1 + b1) -> Hm
  gemm_bf16<0><<<dim3(FFN / 128, CAP / 128, NEXP), 256, 0, stream>>>(
      Amoe, W1T, Hm, b1, CAP, FFN, DM,
      (long long)CAP * DM, (long long)FFN * DM, (long long)CAP * FFN, FFN);
  // 14. FFN2: (Hm @ w2 + b2)*0.8 -> Y
  gemm_bf16<1><<<dim3(DM / 128, CAP / 128, NEXP), 256, 0, stream>>>(
      Hm, W2T, Y, b2, CAP, DM, FFN,
      (long long)CAP * FFN, (long long)DM * FFN, (long long)CAP * DM, DM);
  // 15. combine with gates + residual
  combine<<<T_TOK, 64, 0, stream>>>(x2, Y, e1a, s1a, g1a, e2a, s2a, g2a, out);
}

// Round 5
// 719.371 us; speedup vs baseline: 1.0577x; 1.0577x over previous
//
#include <hip/hip_runtime.h>
#include <hip/hip_bf16.h>
#include <stdint.h>

#define T_TOK 2048
#define DM 1024
#define NHEAD 16
#define HDIM 64
#define SEQ 512
#define NEXP 8
#define FFN 4096
#define CAP 512
#define LN_EPSV 1e-5f
#define ROUTER_EPS 1.1920929e-07f

typedef __bf16 bf16x8 __attribute__((ext_vector_type(8)));
typedef float f32x4 __attribute__((ext_vector_type(4)));

// async global->LDS 16B copy. LDS dest must be wave-uniform-base + lane*16
// (our flat-linear layout satisfies this); global src is per-lane.
__device__ __forceinline__ void gld_lds16(const __hip_bfloat16* g, __hip_bfloat16* l) {
  __builtin_amdgcn_global_load_lds(
      (const __attribute__((address_space(1))) void*)g,
      (__attribute__((address_space(3))) void*)l, 16, 0, 0);
}

// XCD-chunked bijective block remap (requires nwg % 8 == 0, true for all our
// MFMA grids). Consecutive remapped ids share an XCD -> L2 reuse of shared
// operand panels. Pure permutation: correctness-neutral.
__device__ __forceinline__ void xcd_remap(int& bx, int& by, int& bz) {
  int gx = gridDim.x, gy = gridDim.y, gz = gridDim.z;
  int nwg = gx * gy * gz;
  int lin = (blockIdx.z * gy + blockIdx.y) * gx + blockIdx.x;
  int q = nwg >> 3;
  int lin2 = (lin & 7) * q + (lin >> 3);
  int gxy = gx * gy;
  bz = lin2 / gxy;
  int rem = lin2 - bz * gxy;
  by = rem / gx;
  bx = rem - by * gx;
}

// ---------------- transpose + fp32->bf16 convert: in [E][R][C] -> out [E][C][R]
__global__ void transpose_cvt(const float* __restrict__ W, __hip_bfloat16* __restrict__ WT,
                              int R, int Cc) {
  __shared__ float tile[32][33];
  int e = blockIdx.z;
  const float* src = W + (size_t)e * R * Cc;
  __hip_bfloat16* dst = WT + (size_t)e * R * Cc;
  int c0 = blockIdx.x * 32, r0 = blockIdx.y * 32;
  int tx = threadIdx.x, ty = threadIdx.y;
#pragma unroll
  for (int i = 0; i < 4; i++) {
    int r = r0 + ty + i * 8;
    tile[ty + i * 8][tx] = src[(size_t)r * Cc + c0 + tx];
  }
  __syncthreads();
#pragma unroll
  for (int i = 0; i < 4; i++) {
    int c = c0 + ty + i * 8;
    dst[(size_t)c * R + r0 + tx] = __float2bfloat16(tile[tx][ty + i * 8]);
  }
}

// ---------------- transpose + split fp32 -> (hi,lo) bf16 pair: [R][C] -> [C][R], *scale
__global__ void transpose_cvt_hp(const float* __restrict__ W, __hip_bfloat16* __restrict__ WH,
                                 __hip_bfloat16* __restrict__ WL, int R, int Cc, float scale) {
  __shared__ float tile[32][33];
  int c0 = blockIdx.x * 32, r0 = blockIdx.y * 32;
  int tx = threadIdx.x, ty = threadIdx.y;
#pragma unroll
  for (int i = 0; i < 4; i++) {
    int r = r0 + ty + i * 8;
    tile[ty + i * 8][tx] = W[(size_t)r * Cc + c0 + tx];
  }
  __syncthreads();
#pragma unroll
  for (int i = 0; i < 4; i++) {
    int c = c0 + ty + i * 8;
    float v = tile[tx][ty + i * 8] * scale;
    __hip_bfloat16 h = __float2bfloat16(v);
    WH[(size_t)c * R + r0 + tx] = h;
    WL[(size_t)c * R + r0 + tx] = __float2bfloat16(v - __bfloat162float(h));
  }
}

// ---------------- pack scaled biases for batched QKV: [bq*0.125 | bk | bv]
__global__ __launch_bounds__(256) void pack_bias(const float* __restrict__ bq,
                                                 const float* __restrict__ bk,
                                                 const float* __restrict__ bv,
                                                 float* __restrict__ outp) {
  int t = blockIdx.x * 256 + threadIdx.x;
  if (t < DM) outp[t] = bq[t] * 0.125f;
  else if (t < 2 * DM) outp[t] = bk[t - DM];
  else if (t < 3 * DM) outp[t] = bv[t - 2 * DM];
}

// ---------------- LayerNorm fp32 -> (hi,lo) bf16 pair, one block per row
__global__ __launch_bounds__(256) void ln1_hp(const float* __restrict__ x,
                                              const float* __restrict__ g,
                                              const float* __restrict__ bta,
                                              __hip_bfloat16* __restrict__ ohi,
                                              __hip_bfloat16* __restrict__ olo) {
  int row = blockIdx.x, t = threadIdx.x;
  const float4* xr = (const float4*)(x + (size_t)row * DM);
  float4 v = xr[t];
  float s = v.x + v.y + v.z + v.w;
  float ss = v.x * v.x + v.y * v.y + v.z * v.z + v.w * v.w;
  __shared__ float rs[4], rss[4];
  __shared__ float smu, sinv;
  int wid = t >> 6, lane = t & 63;
  for (int off = 32; off; off >>= 1) { s += __shfl_down(s, off); ss += __shfl_down(ss, off); }
  if (!lane) { rs[wid] = s; rss[wid] = ss; }
  __syncthreads();
  if (!t) {
    float S = rs[0] + rs[1] + rs[2] + rs[3], SS = rss[0] + rss[1] + rss[2] + rss[3];
    float mu = S / DM;
    float var = SS / DM - mu * mu;
    smu = mu; sinv = 1.0f / sqrtf(var + LN_EPSV);
  }
  __syncthreads();
  float mu = smu, inv = sinv;
  float4 gv = ((const float4*)g)[t], bv = ((const float4*)bta)[t];
  float n[4];
  n[0] = (v.x - mu) * inv * gv.x + bv.x;
  n[1] = (v.y - mu) * inv * gv.y + bv.y;
  n[2] = (v.z - mu) * inv * gv.z + bv.z;
  n[3] = (v.w - mu) * inv * gv.w + bv.w;
  __hip_bfloat16* hr = ohi + (size_t)row * DM + t * 4;
  __hip_bfloat16* lr = olo + (size_t)row * DM + t * 4;
#pragma unroll
  for (int k = 0; k < 4; k++) {
    __hip_bfloat16 h = __float2bfloat16(n[k]);
    hr[k] = h;
    lr[k] = __float2bfloat16(n[k] - __bfloat162float(h));
  }
}

// ---------------- fp32 -> (hi,lo) bf16 split convert
__global__ __launch_bounds__(256) void cvt_hp(const float* __restrict__ in,
                                              __hip_bfloat16* __restrict__ hi,
                                              __hip_bfloat16* __restrict__ lo) {
  int i = (blockIdx.x * 256 + threadIdx.x) * 4;
  float4 v = *(const float4*)&in[i];
  float n[4] = {v.x, v.y, v.z, v.w};
#pragma unroll
  for (int k = 0; k < 4; k++) {
    __hip_bfloat16 h = __float2bfloat16(n[k]);
    hi[i + k] = h;
    lo[i + k] = __float2bfloat16(n[k] - __bfloat162float(h));
  }
}

// ---------------- fp32 tiled GEMM. C = (A@B(^T) + bias)*scale + resid
template <int BM, int BN, int TM, int TN, bool BT>
__global__ __launch_bounds__(256) void gemm_f32(
    const float* __restrict__ A, const float* __restrict__ B, float* __restrict__ Cc,
    const float* __restrict__ bias, const float* __restrict__ resid,
    int M, int N, int K, int lda, int ldb, int ldc, float scale, int zdiv,
    long long sA1, long long sA2, long long sB1, long long sB2,
    long long sC1, long long sC2) {
  constexpr int BK = 16;
  __shared__ float As[BK][BM + 4];
  __shared__ float Bs[BK][BN + 4];
  int z = blockIdx.z;
  int zq = z / zdiv, zr = z % zdiv;
  A += zq * sA1 + zr * sA2;
  B += zq * sB1 + zr * sB2;
  Cc += zq * sC1 + zr * sC2;
  int tid = threadIdx.x;
  int m0 = blockIdx.y * BM, n0 = blockIdx.x * BN;
  constexpr int NTX = BN / TN;
  int tx = tid % NTX, ty = tid / NTX;
  float acc[TM][TN] = {};
  for (int k0 = 0; k0 < K; k0 += BK) {
    constexpr int ALOADS = BM * BK / (256 * 4);
#pragma unroll
    for (int i = 0; i < ALOADS; i++) {
      int idx = tid + i * 256;
      int m = idx / (BK / 4);
      int kk = (idx % (BK / 4)) * 4;
      float4 va = *(const float4*)&A[(size_t)(m0 + m) * lda + k0 + kk];
      As[kk + 0][m] = va.x; As[kk + 1][m] = va.y; As[kk + 2][m] = va.z; As[kk + 3][m] = va.w;
    }
    constexpr int BLOADS = BK * BN / (256 * 4);
    if (!BT) {
#pragma unroll
      for (int i = 0; i < BLOADS; i++) {
        int idx = tid + i * 256;
        int kk = idx / (BN / 4);
        int n = (idx % (BN / 4)) * 4;
        *(float4*)&Bs[kk][n] = *(const float4*)&B[(size_t)(k0 + kk) * ldb + n0 + n];
      }
    } else {
#pragma unroll
      for (int i = 0; i < BLOADS; i++) {
        int idx = tid + i * 256;
        int n = idx / (BK / 4);
        int kk = (idx % (BK / 4)) * 4;
        float4 vb = *(const float4*)&B[(size_t)(n0 + n) * ldb + k0 + kk];
        Bs[kk + 0][n] = vb.x; Bs[kk + 1][n] = vb.y; Bs[kk + 2][n] = vb.z; Bs[kk + 3][n] = vb.w;
      }
    }
    __syncthreads();
#pragma unroll
    for (int kk = 0; kk < BK; kk++) {
      float ar[TM], br[TN];
#pragma unroll
      for (int i = 0; i < TM; i += 4) *(float4*)&ar[i] = *(const float4*)&As[kk][ty * TM + i];
#pragma unroll
      for (int j = 0; j < TN; j += 4) *(float4*)&br[j] = *(const float4*)&Bs[kk][tx * TN + j];
#pragma unroll
      for (int i = 0; i < TM; i++)
#pragma unroll
        for (int j = 0; j < TN; j++) acc[i][j] += ar[i] * br[j];
    }
    __syncthreads();
  }
#pragma unroll
  for (int i = 0; i < TM; i++) {
    int m = m0 + ty * TM + i;
#pragma unroll
    for (int j = 0; j < TN; j++) {
      int n = n0 + tx * TN + j;
      float v = acc[i][j];
      if (bias) v += bias[n];
      v *= scale;
      if (resid) v += resid[(size_t)m * ldc + n];
      acc[i][j] = v;
    }
#pragma unroll
    for (int j = 0; j < TN; j += 4)
      *(float4*)&Cc[(size_t)m * ldc + n0 + tx * TN + j] = *(float4*)&acc[i][j];
  }
}

// ---------------- row softmax in place (rows of 512 fp32)
__global__ __launch_bounds__(256) void softmax_rows(float* __restrict__ sc) {
  int row = blockIdx.x, t = threadIdx.x;
  float* p = sc + (size_t)row * SEQ;
  float2 v = *(const float2*)&p[t * 2];
  float mx = fmaxf(v.x, v.y);
  __shared__ float r[4];
  __shared__ float bmax, bsum;
  int wid = t >> 6, lane = t & 63;
  for (int off = 32; off; off >>= 1) mx = fmaxf(mx, __shfl_down(mx, off));
  if (!lane) r[wid] = mx;
  __syncthreads();
  if (!t) bmax = fmaxf(fmaxf(r[0], r[1]), fmaxf(r[2], r[3]));
  __syncthreads();
  mx = bmax;
  float e0 = __expf(v.x - mx), e1v = __expf(v.y - mx);
  float s = e0 + e1v;
  for (int off = 32; off; off >>= 1) s += __shfl_down(s, off);
  if (!lane) r[wid] = s;
  __syncthreads();
  if (!t) bsum = r[0] + r[1] + r[2] + r[3];
  __syncthreads();
  float inv = 1.0f / bsum;
  float2 o; o.x = e0 * inv; o.y = e1v * inv;
  *(float2*)&p[t * 2] = o;
}

// ---------------- split-precision bf16 MFMA GEMM (fp32-accurate), double-buffered,
// templated tile geometry. C = A @ Bt^T + bias (+resid), A=Ahi+Alo, Bt=Bhi+Blo.
// acc += AhiBhi + AhiBlo + AloBhi. BK=32 (one MFMA K-fragment per step).
// MODE 2: (acc+bias) -> fp32 ; MODE 3: (acc+bias)+resid -> fp32
template <int MODE, int BM, int BN, int WM, int WN>
__global__ __launch_bounds__(256) void gemm_hp(
    const __hip_bfloat16* __restrict__ Ahi, const __hip_bfloat16* __restrict__ Alo,
    const __hip_bfloat16* __restrict__ Bhi, const __hip_bfloat16* __restrict__ Blo,
    float* __restrict__ Cc, const float* __restrict__ bias, const float* __restrict__ resid,
    int M, int N, int K, long long sB, long long sC, int biasStride) {
  constexpr int BK = 32;
  constexpr int MI = BM / WM / 16, NJ = BN / WN / 16;
  __shared__ __align__(16) __hip_bfloat16 AsH[2][BM * BK];
  __shared__ __align__(16) __hip_bfloat16 AsL[2][BM * BK];
  __shared__ __align__(16) __hip_bfloat16 BsH[2][BN * BK];
  __shared__ __align__(16) __hip_bfloat16 BsL[2][BN * BK];
  int bx, by, bz;
  xcd_remap(bx, by, bz);
  int e = bz;
  Bhi += (size_t)e * sB; Blo += (size_t)e * sB;
  size_t czoff = (size_t)e * sC;
  const float* bvec = bias + (size_t)e * biasStride;
  int m0 = by * BM, n0 = bx * BN;
  int tid = threadIdx.x;
  int lane = tid & 63, quad = lane >> 4, l16 = lane & 15, wv = tid >> 6;
  int wm = wv / WN, wn = wv % WN;
  f32x4 acc[MI][NJ] = {};
  // staging: linear LDS dest, swizzle folded into GLOBAL source chunk.
  // pc = lc ^ ((r>>1)&3): 2-way bank aliasing on ds_read (free).
  auto STAGE = [&](int buf, int k0) {
    constexpr int ACH = BM * (BK / 8) / 256;
#pragma unroll
    for (int i = 0; i < ACH; i++) {
      int flat = tid + i * 256;
      int r = flat >> 2, lc = flat & 3;
      int pc = lc ^ ((r >> 1) & 3);
      gld_lds16(Ahi + (size_t)(m0 + r) * K + k0 + pc * 8, &AsH[buf][flat * 8]);
      gld_lds16(Alo + (size_t)(m0 + r) * K + k0 + pc * 8, &AsL[buf][flat * 8]);
    }
    constexpr int BCH = BN * (BK / 8) / 256;
#pragma unroll
    for (int i = 0; i < BCH; i++) {
      int flat = tid + i * 256;
      int r = flat >> 2, lc = flat & 3;
      int pc = lc ^ ((r >> 1) & 3);
      gld_lds16(Bhi + (size_t)(n0 + r) * K + k0 + pc * 8, &BsH[buf][flat * 8]);
      gld_lds16(Blo + (size_t)(n0 + r) * K + k0 + pc * 8, &BsL[buf][flat * 8]);
    }
  };
  STAGE(0, 0);
  __syncthreads();
  int KT = K / BK;
  for (int kt = 0; kt < KT; kt++) {
    int cur = kt & 1;
    // ds_read FIRST (no vmcnt dependence possible), then issue next-tile stage
    bf16x8 ah[MI], al[MI], bh[NJ], bl[NJ];
#pragma unroll
    for (int i = 0; i < MI; i++) {
      int r = wm * (BM / WM) + i * 16 + l16;
      int pc = quad ^ ((r >> 1) & 3);
      ah[i] = *(const bf16x8*)(&AsH[cur][r * BK + pc * 8]);
      al[i] = *(const bf16x8*)(&AsL[cur][r * BK + pc * 8]);
    }
#pragma unroll
    for (int j = 0; j < NJ; j++) {
      int r = wn * (BN / WN) + j * 16 + l16;
      int pc = quad ^ ((r >> 1) & 3);
      bh[j] = *(const bf16x8*)(&BsH[cur][r * BK + pc * 8]);
      bl[j] = *(const bf16x8*)(&BsL[cur][r * BK + pc * 8]);
    }
    __builtin_amdgcn_sched_barrier(0);
    if (kt + 1 < KT) STAGE(cur ^ 1, (kt + 1) * BK);  // overlaps MFMA below
#pragma unroll
    for (int i = 0; i < MI; i++)
#pragma unroll
      for (int j = 0; j < NJ; j++) {
        acc[i][j] = __builtin_amdgcn_mfma_f32_16x16x32_bf16(ah[i], bh[j], acc[i][j], 0, 0, 0);
        acc[i][j] = __builtin_amdgcn_mfma_f32_16x16x32_bf16(ah[i], bl[j], acc[i][j], 0, 0, 0);
        acc[i][j] = __builtin_amdgcn_mfma_f32_16x16x32_bf16(al[i], bh[j], acc[i][j], 0, 0, 0);
      }
    __syncthreads();  // drains prefetch + protects cur from next overwrite
  }
#pragma unroll
  for (int j = 0; j < NJ; j++) {
    int col = n0 + wn * (BN / WN) + j * 16 + l16;
    float bb = bvec[col];
#pragma unroll
    for (int i = 0; i < MI; i++) {
      int row0 = m0 + wm * (BM / WM) + i * 16 + quad * 4;
#pragma unroll
      for (int r = 0; r < 4; r++) {
        float v = acc[i][j][r] + bb;
        if (MODE == 3) v += resid[(size_t)(row0 + r) * N + col];
        Cc[czoff + (size_t)(row0 + r) * N + col] = v;
      }
    }
  }
}

// ---------------- LN2 fused with router logits; writes h2 (bf16) and logits (fp32)
__global__ __launch_bounds__(256) void ln2_router(const float* __restrict__ x2,
                                                  const float* __restrict__ g,
                                                  const float* __restrict__ bta,
                                                  const float* __restrict__ wr,
                                                  __hip_bfloat16* __restrict__ h2,
                                                  float* __restrict__ logits) {
  int row = blockIdx.x, t = threadIdx.x;
  const float4* xr = (const float4*)(x2 + (size_t)row * DM);
  float4 v = xr[t];
  float s = v.x + v.y + v.z + v.w;
  float ss = v.x * v.x + v.y * v.y + v.z * v.z + v.w * v.w;
  __shared__ float rs[4], rss[4];
  __shared__ float smu, sinv;
  int wid = t >> 6, lane = t & 63;
  for (int off = 32; off; off >>= 1) { s += __shfl_down(s, off); ss += __shfl_down(ss, off); }
  if (!lane) { rs[wid] = s; rss[wid] = ss; }
  __syncthreads();
  if (!t) {
    float S = rs[0] + rs[1] + rs[2] + rs[3], SS = rss[0] + rss[1] + rss[2] + rss[3];
    float mu = S / DM;
    float var = SS / DM - mu * mu;
    smu = mu; sinv = 1.0f / sqrtf(var + LN_EPSV);
  }
  __syncthreads();
  float mu = smu, inv = sinv;
  float4 gv = ((const float4*)g)[t], bv = ((const float4*)bta)[t];
  float n0 = (v.x - mu) * inv * gv.x + bv.x;
  float n1 = (v.y - mu) * inv * gv.y + bv.y;
  float n2 = (v.z - mu) * inv * gv.z + bv.z;
  float n3 = (v.w - mu) * inv * gv.w + bv.w;
  __hip_bfloat16* hr = h2 + (size_t)row * DM + t * 4;
  hr[0] = __float2bfloat16(n0); hr[1] = __float2bfloat16(n1);
  hr[2] = __float2bfloat16(n2); hr[3] = __float2bfloat16(n3);
  const float* w0 = wr + (size_t)(t * 4) * NEXP;
  __shared__ float red[256 * NEXP];
#pragma unroll
  for (int e = 0; e < NEXP; e++)
    red[t * NEXP + e] = n0 * w0[e] + n1 * w0[NEXP + e] + n2 * w0[2 * NEXP + e] + n3 * w0[3 * NEXP + e];
  __syncthreads();
  for (int sdt = 128; sdt > 0; sdt >>= 1) {
    if (t < sdt) {
#pragma unroll
      for (int e = 0; e < NEXP; e++) red[t * NEXP + e] += red[(t + sdt) * NEXP + e];
    }
    __syncthreads();
  }
  if (t < NEXP) logits[(size_t)row * NEXP + t] = red[t];
}

// ---------------- routing: top1/top2, deterministic capacity ranks, gates, dispatch map
__global__ __launch_bounds__(256) void routing(const float* __restrict__ logits,
                                               int* __restrict__ e1o, int* __restrict__ s1o,
                                               float* __restrict__ g1o,
                                               int* __restrict__ e2o, int* __restrict__ s2o,
                                               float* __restrict__ g2o,
                                               int* __restrict__ src_tok) {
  __shared__ unsigned char t1s[T_TOK], t2s[T_TOK];
  __shared__ unsigned short r1s[T_TOK], r2s[T_TOK];
  __shared__ int cnt1s[NEXP];
  int t = threadIdx.x;
  for (int i = t; i < NEXP * CAP; i += 256) src_tok[i] = -1;
  for (int tok = t; tok < T_TOK; tok += 256) {
    float lg[NEXP];
#pragma unroll
    for (int e = 0; e < NEXP; e++) lg[e] = logits[(size_t)tok * NEXP + e];
    int b1 = 0; float m1v = lg[0];
#pragma unroll
    for (int e = 1; e < NEXP; e++) if (lg[e] > m1v) { m1v = lg[e]; b1 = e; }
    int b2 = -1; float m2v = -3.4e38f;
#pragma unroll
    for (int e = 0; e < NEXP; e++) if (e != b1 && lg[e] > m2v) { m2v = lg[e]; b2 = e; }
    t1s[tok] = (unsigned char)b1; t2s[tok] = (unsigned char)b2;
  }
  __syncthreads();
  if (t < 64) {
    int base[NEXP] = {0, 0, 0, 0, 0, 0, 0, 0};
    for (int c = 0; c < T_TOK / 64; c++) {
      int tok = c * 64 + t;
      int my = t1s[tok];
      unsigned long long below = (1ull << t) - 1ull;
#pragma unroll
      for (int e = 0; e < NEXP; e++) {
        unsigned long long msk = __ballot(my == e);
        if (my == e) r1s[tok] = (unsigned short)(base[e] + __popcll(msk & below));
        base[e] += (int)__popcll(msk);
      }
    }
    if (t == 0) {
#pragma unroll
      for (int e = 0; e < NEXP; e++) cnt1s[e] = base[e];
    }
#pragma unroll
    for (int e = 0; e < NEXP; e++) base[e] = 0;
    for (int c = 0; c < T_TOK / 64; c++) {
      int tok = c * 64 + t;
      int my = t2s[tok];
      unsigned long long below = (1ull << t) - 1ull;
#pragma unroll
      for (int e = 0; e < NEXP; e++) {
        unsigned long long msk = __ballot(my == e);
        if (my == e) r2s[tok] = (unsigned short)(base[e] + __popcll(msk & below));
        base[e] += (int)__popcll(msk);
      }
    }
  }
  __syncthreads();
  for (int tok = t; tok < T_TOK; tok += 256) {
    float lg[NEXP];
#pragma unroll
    for (int e = 0; e < NEXP; e++) lg[e] = logits[(size_t)tok * NEXP + e];
    int b1 = t1s[tok], b2 = t2s[tok];
    float lb1 = lg[0], lb2 = lg[0];
#pragma unroll
    for (int e = 0; e < NEXP; e++) { if (e == b1) lb1 = lg[e]; if (e == b2) lb2 = lg[e]; }
    float sum = 0.f;
#pragma unroll
    for (int e = 0; e < NEXP; e++) sum += __expf(lg[e] - lb1);
    float p1 = 1.0f / sum;
    float p2 = __expf(lb2 - lb1) / sum;
    int sl1 = r1s[tok];
    int sl2 = r2s[tok] + cnt1s[b2];
    bool v1 = sl1 < CAP, v2 = sl2 < CAP;
    float tt1 = v1 ? p1 : 0.f, tt2 = v2 ? p2 : 0.f;
    float den = fmaxf(tt1 + tt2, ROUTER_EPS);
    float gg1 = v1 ? tt1 / den : 0.f;
    float gg2 = v2 ? tt2 / den : 0.f;
    e1o[tok] = b1; s1o[tok] = v1 ? sl1 : 0; g1o[tok] = gg1;
    e2o[tok] = b2; s2o[tok] = v2 ? sl2 : 0; g2o[tok] = gg2;
    if (v1) src_tok[b1 * CAP + sl1] = tok;
    if (v2) src_tok[b2 * CAP + sl2] = tok;
  }
}

// ---------------- dispatch h2 rows into [E*CAP, DM] bf16 buffers (zero unfilled)
__global__ __launch_bounds__(64) void dispatch(const int* __restrict__ src_tok,
                                               const __hip_bfloat16* __restrict__ h2,
                                               __hip_bfloat16* __restrict__ Amoe) {
  int rowb = blockIdx.x, t = threadIdx.x;
  int tok = src_tok[rowb];
  uint4* dst = (uint4*)(Amoe + (size_t)rowb * DM);
  if (tok >= 0) {
    const uint4* src = (const uint4*)(h2 + (size_t)tok * DM);
    dst[t] = src[t]; dst[t + 64] = src[t + 64];
  } else {
    uint4 z = make_uint4(0, 0, 0, 0);
    dst[t] = z; dst[t + 64] = z;
  }
}

// ---------------- bf16 MFMA GEMM, templated tile geometry + buffering.
// C = epi(A @ Bt^T + bias); A [M,K], Bt [N,K]. BK=64.
// MODE 0: relu(acc+bias) -> bf16 ; MODE 1: (acc+bias)*0.8 -> bf16
// DB=1: double-buffered (for <=2-3 blocks/CU grids); DB=0: single buffer
// (32KB -> lets 4+ blocks/CU grids actually co-reside; TLP hides latency).
template <int MODE, int BM, int BN, int WM, int WN, int DB>
__global__ __launch_bounds__(256) void gemm_bf16(
    const __hip_bfloat16* __restrict__ A, const __hip_bfloat16* __restrict__ Bt,
    __hip_bfloat16* __restrict__ Cc, const float* __restrict__ bias,
    int M, int N, int K, long long sA, long long sB, long long sC, int biasStride) {
  constexpr int BK = 64;
  constexpr int NB = DB ? 2 : 1;
  constexpr int MI = BM / WM / 16, NJ = BN / WN / 16;
  __shared__ __align__(16) __hip_bfloat16 Asm[NB][BM * BK];
  __shared__ __align__(16) __hip_bfloat16 Bsm[NB][BN * BK];
  int bx, by, bz;
  xcd_remap(bx, by, bz);
  int e = bz;
  A += (size_t)e * sA; Bt += (size_t)e * sB; Cc += (size_t)e * sC;
  const float* bvec = bias + (size_t)e * biasStride;
  int m0 = by * BM, n0 = bx * BN;
  int tid = threadIdx.x;
  int lane = tid & 63, quad = lane >> 4, l16 = lane & 15, wv = tid >> 6;
  int wm = wv / WN, wn = wv % WN;
  f32x4 acc[MI][NJ] = {};
  auto STAGE = [&](int buf, int k0) {
    constexpr int ACH = BM * (BK / 8) / 256;
#pragma unroll
    for (int i = 0; i < ACH; i++) {
      int flat = tid + i * 256;
      int r = flat >> 3, lc = flat & 7;
      int pc = lc ^ (r & 7);          // swizzle folded into global source chunk
      gld_lds16(A + (size_t)(m0 + r) * K + k0 + pc * 8, &Asm[buf][flat * 8]);
    }
    constexpr int BCH = BN * (BK / 8) / 256;
#pragma unroll
    for (int i = 0; i < BCH; i++) {
      int flat = tid + i * 256;
      int r = flat >> 3, lc = flat & 7;
      int pc = lc ^ (r & 7);
      gld_lds16(Bt + (size_t)(n0 + r) * K + k0 + pc * 8, &Bsm[buf][flat * 8]);
    }
  };
  int KT = K / BK;
  if (DB) {
    STAGE(0, 0);
    __syncthreads();
    for (int kt = 0; kt < KT; kt++) {
      int cur = kt & 1;
      // ds_read FIRST, then issue next-tile stage, then MFMA
      bf16x8 af[2][MI], bfr[2][NJ];
#pragma unroll
      for (int ks = 0; ks < 2; ks++) {
#pragma unroll
        for (int i = 0; i < MI; i++) {
          int r = wm * (BM / WM) + i * 16 + l16;
          int pc = (ks * 4 + quad) ^ (r & 7);
          af[ks][i] = *(const bf16x8*)(&Asm[cur][r * BK + pc * 8]);
        }
#pragma unroll
        for (int j = 0; j < NJ; j++) {
          int r = wn * (BN / WN) + j * 16 + l16;
          int pc = (ks * 4 + quad) ^ (r & 7);
          bfr[ks][j] = *(const bf16x8*)(&Bsm[cur][r * BK + pc * 8]);
        }
      }
      __builtin_amdgcn_sched_barrier(0);
      if (kt + 1 < KT) STAGE(cur ^ 1, (kt + 1) * BK);  // overlaps MFMA below
#pragma unroll
      for (int ks = 0; ks < 2; ks++)
#pragma unroll
        for (int i = 0; i < MI; i++)
#pragma unroll
          for (int j = 0; j < NJ; j++)
            acc[i][j] = __builtin_amdgcn_mfma_f32_16x16x32_bf16(af[ks][i], bfr[ks][j], acc[i][j], 0, 0, 0);
      __syncthreads();
    }
  } else {
    for (int kt = 0; kt < KT; kt++) {
      if (kt) __syncthreads();
      STAGE(0, kt * BK);
      __syncthreads();
#pragma unroll
      for (int ks = 0; ks < 2; ks++) {
        bf16x8 af[MI], bfr[NJ];
#pragma unroll
        for (int i = 0; i < MI; i++) {
          int r = wm * (BM / WM) + i * 16 + l16;
          int pc = (ks * 4 + quad) ^ (r & 7);
          af[i] = *(const bf16x8*)(&Asm[0][r * BK + pc * 8]);
        }
#pragma unroll
        for (int j = 0; j < NJ; j++) {
          int r = wn * (BN / WN) + j * 16 + l16;
          int pc = (ks * 4 + quad) ^ (r & 7);
          bfr[j] = *(const bf16x8*)(&Bsm[0][r * BK + pc * 8]);
        }
#pragma unroll
        for (int i = 0; i < MI; i++)
#pragma unroll
          for (int j = 0; j < NJ; j++)
            acc[i][j] = __builtin_amdgcn_mfma_f32_16x16x32_bf16(af[i], bfr[j], acc[i][j], 0, 0, 0);
      }
    }
  }
#pragma unroll
  for (int j = 0; j < NJ; j++) {
    int col = n0 + wn * (BN / WN) + j * 16 + l16;
    float bb = bvec[col];
#pragma unroll
    for (int i = 0; i < MI; i++) {
      int row0 = m0 + wm * (BM / WM) + i * 16 + quad * 4;
#pragma unroll
      for (int r = 0; r < 4; r++) {
        float v = acc[i][j][r] + bb;
        if (MODE == 0) v = fmaxf(v, 0.0f);
        else v *= 0.8f;
        Cc[(size_t)(row0 + r) * N + col] = __float2bfloat16(v);
      }
    }
  }
}

// ---------------- combine: out = x2 + g1*Y[e1,s1] + g2*Y[e2,s2]
__global__ __launch_bounds__(64) void combine(const float* __restrict__ x2,
                                              const __hip_bfloat16* __restrict__ Y,
                                              const int* __restrict__ e1, const int* __restrict__ s1,
                                              const float* __restrict__ g1,
                                              const int* __restrict__ e2, const int* __restrict__ s2,
                                              const float* __restrict__ g2,
                                              float* __restrict__ out) {
  int tok = blockIdx.x, t = threadIdx.x;
  float gg1 = g1[tok], gg2 = g2[tok];
  const __hip_bfloat16* y1 = Y + ((size_t)e1[tok] * CAP + s1[tok]) * DM;
  const __hip_bfloat16* y2 = Y + ((size_t)e2[tok] * CAP + s2[tok]) * DM;
  const float* xr = x2 + (size_t)tok * DM;
  float* orow = out + (size_t)tok * DM;
#pragma unroll
  for (int j = 0; j < 4; j++) {
    int idx = t * 4 + j * 256;
    float4 vv = *(const float4*)&xr[idx];
    float4 r;
    r.x = vv.x + gg1 * __bfloat162float(y1[idx + 0]) + gg2 * __bfloat162float(y2[idx + 0]);
    r.y = vv.y + gg1 * __bfloat162float(y1[idx + 1]) + gg2 * __bfloat162float(y2[idx + 1]);
    r.z = vv.z + gg1 * __bfloat162float(y1[idx + 2]) + gg2 * __bfloat162float(y2[idx + 2]);
    r.w = vv.w + gg1 * __bfloat162float(y1[idx + 3]) + gg2 * __bfloat162float(y2[idx + 3]);
    *(float4*)&orow[idx] = r;
  }
}

extern "C" void kernel_launch(void* const* d_in, const int* in_sizes, int n_in,
                              void* d_out, int out_size, void* d_ws, size_t ws_size,
                              hipStream_t stream) {
  (void)in_sizes; (void)n_in; (void)out_size; (void)ws_size;
  const float* x    = (const float*)d_in[0];
  const float* wq   = (const float*)d_in[1];
  const float* bq   = (const float*)d_in[2];
  const float* wk   = (const float*)d_in[3];
  const float* bk   = (const float*)d_in[4];
  const float* wv   = (const float*)d_in[5];
  const float* bv   = (const float*)d_in[6];
  const float* wo   = (const float*)d_in[7];
  const float* bo   = (const float*)d_in[8];
  const float* ln1g = (const float*)d_in[9];
  const float* ln1b = (const float*)d_in[10];
  const float* ln2g = (const float*)d_in[11];
  const float* ln2b = (const float*)d_in[12];
  const float* wr   = (const float*)d_in[13];
  const float* w1   = (const float*)d_in[14];
  const float* b1   = (const float*)d_in[15];
  const float* w2   = (const float*)d_in[16];
  const float* b2   = (const float*)d_in[17];
  float* out = (float*)d_out;
  char* ws = (char*)d_ws;

  // ---------------- workspace arena (max ~230 MB; regions reused once dead)
  __hip_bfloat16* W1T  = (__hip_bfloat16*)(ws + 0);
  __hip_bfloat16* W2T  = (__hip_bfloat16*)(ws + 67108864);
  float* sc            = (float*)(ws + 134217728);
  __hip_bfloat16* h1hi = (__hip_bfloat16*)(ws + 134217728);
  __hip_bfloat16* h1lo = (__hip_bfloat16*)(ws + 138412032);
  float* bqkv          = (float*)(ws + 142606336);
  __hip_bfloat16* WQKVH= (__hip_bfloat16*)(ws + 143654912);
  __hip_bfloat16* WQKVL= (__hip_bfloat16*)(ws + 149946368);
  __hip_bfloat16* Hm   = (__hip_bfloat16*)(ws + 134217728);
  float* logits        = (float*)(ws + 167772160);
  int*   e1a           = (int*)(ws + 167837696);
  int*   s1a           = (int*)(ws + 167845888);
  int*   e2a           = (int*)(ws + 167854080);
  int*   s2a           = (int*)(ws + 167862272);
  float* g1a           = (float*)(ws + 167870464);
  float* g2a           = (float*)(ws + 167878656);
  int*   src_tok       = (int*)(ws + 167886848);
  float* qkv           = (float*)(ws + 201326592);
  float* q             = qkv;
  float* k_            = qkv + 2097152;
  float* v             = qkv + 4194304;
  float* o_f           = (float*)(ws + 201326592);
  float* x2            = (float*)(ws + 201326592);
  __hip_bfloat16* ohi  = (__hip_bfloat16*)(ws + 209715200);
  __hip_bfloat16* olo  = (__hip_bfloat16*)(ws + 213909504);
  __hip_bfloat16* Y    = (__hip_bfloat16*)(ws + 209715200);
  __hip_bfloat16* h2   = (__hip_bfloat16*)(ws + 218103808);
  __hip_bfloat16* Amoe = (__hip_bfloat16*)(ws + 222298112);
  __hip_bfloat16* WOH  = (__hip_bfloat16*)(ws + 226492416);
  __hip_bfloat16* WOL  = (__hip_bfloat16*)(ws + 228589568);

  // 1. MoE weight convert+transpose (plain bf16 — post-routing path)
  transpose_cvt<<<dim3(FFN / 32, DM / 32, NEXP), dim3(32, 8), 0, stream>>>(w1, W1T, DM, FFN);
  transpose_cvt<<<dim3(DM / 32, FFN / 32, NEXP), dim3(32, 8), 0, stream>>>(w2, W2T, FFN, DM);
  // 2. attention weight transposes -> split hi/lo bf16 [N,K]; fold 0.125 into wq
  transpose_cvt_hp<<<dim3(DM / 32, DM / 32, 1), dim3(32, 8), 0, stream>>>(
      wq, WQKVH, WQKVL, DM, DM, 0.125f);
  transpose_cvt_hp<<<dim3(DM / 32, DM / 32, 1), dim3(32, 8), 0, stream>>>(
      wk, WQKVH + (size_t)DM * DM, WQKVL + (size_t)DM * DM, DM, DM, 1.0f);
  transpose_cvt_hp<<<dim3(DM / 32, DM / 32, 1), dim3(32, 8), 0, stream>>>(
      wv, WQKVH + (size_t)2 * DM * DM, WQKVL + (size_t)2 * DM * DM, DM, DM, 1.0f);
  transpose_cvt_hp<<<dim3(DM / 32, DM / 32, 1), dim3(32, 8), 0, stream>>>(
      wo, WOH, WOL, DM, DM, 1.0f);
  pack_bias<<<3 * DM / 256, 256, 0, stream>>>(bq, bk, bv, bqkv);
  // 3. LN1 -> split hi/lo bf16
  ln1_hp<<<T_TOK, 256, 0, stream>>>(x, ln1g, ln1b, h1hi, h1lo);
  // 4. batched Q,K,V projections (split-precision MFMA) -> fp32. 768 blocks = 3/CU.
  gemm_hp<2, 128, 64, 2, 2><<<dim3(DM / 64, T_TOK / 128, 3), 256, 0, stream>>>(
      h1hi, h1lo, WQKVH, WQKVL, qkv, bqkv, nullptr, T_TOK, DM, DM,
      (long long)DM * DM, (long long)T_TOK * DM, DM);
  // 5. scores = Q K^T per head (fp32)
  gemm_f32<128, 128, 8, 8, true><<<dim3(SEQ / 128, SEQ / 128, 64), 256, 0, stream>>>(
      q, k_, sc, nullptr, nullptr, SEQ, SEQ, HDIM, DM, DM, SEQ, 1.0f, NHEAD,
      (long long)SEQ * DM, HDIM, (long long)SEQ * DM, HDIM,
      (long long)NHEAD * SEQ * SEQ, (long long)SEQ * SEQ);
  // 6. softmax rows
  softmax_rows<<<64 * SEQ, 256, 0, stream>>>(sc);
  // 7. O = P V per head (fp32)
  gemm_f32<128, 64, 8, 4, false><<<dim3(1, SEQ / 128, 64), 256, 0, stream>>>(
      sc, v, o_f, nullptr, nullptr, SEQ, HDIM, SEQ, SEQ, DM, DM, 1.0f, NHEAD,
      (long long)NHEAD * SEQ * SEQ, (long long)SEQ * SEQ,
      (long long)SEQ * DM, HDIM, (long long)SEQ * DM, HDIM);
  // 8. split O to hi/lo bf16
  cvt_hp<<<T_TOK * DM / 1024, 256, 0, stream>>>(o_f, ohi, olo);
  // 9. O-proj (split-precision MFMA) + residual -> x2 fp32. 512 blocks = 2/CU.
  gemm_hp<3, 64, 64, 2, 2><<<dim3(DM / 64, T_TOK / 64, 1), 256, 0, stream>>>(
      ohi, olo, WOH, WOL, x2, bo, x, T_TOK, DM, DM, 0LL, 0LL, 0);
  // 10. LN2 + router logits
  ln2_router<<<T_TOK, 256, 0, stream>>>(x2, ln2g, ln2b, wr, h2, logits);
  // 11. routing decisions
  routing<<<1, 256, 0, stream>>>(logits, e1a, s1a, g1a, e2a, s2a, g2a, src_tok);
  // 12. dispatch to expert capacity buffers
  dispatch<<<NEXP * CAP, 64, 0, stream>>>(src_tok, h2, Amoe);
  // 13. FFN1: relu(Amoe @ w1 + b1) -> Hm. 1024 blocks; single-buf 32KB -> 4-5 blocks/CU.
  gemm_bf16<0, 128, 128, 2, 2, 0><<<dim3(FFN / 128, CAP / 128, NEXP), 256, 0, stream>>>(
      Amoe, W1T, Hm, b1, CAP, FFN, DM,
      (long long)CAP * DM, (long long)FFN * DM, (long long)CAP * FFN, FFN);
  // 14. FFN2: (Hm @ w2 + b2)*0.8 -> Y. 512 blocks = 2/CU, dbuf.
  gemm_bf16<1, 128, 64, 2, 2, 1><<<dim3(DM / 64, CAP / 128, NEXP), 256, 0, stream>>>(
      Hm, W2T, Y, b2, CAP, DM, FFN,
      (long long)CAP * FFN, (long long)DM * FFN, (long long)CAP * DM, DM);
  // 15. combine with gates + residual
  combine<<<T_TOK, 64, 0, stream>>>(x2, Y, e1a, s1a, g1a, e2a, s2a, g2a, out);
}